// Round 16
// baseline (158.616 us; speedup 1.0000x reference)
//
#include <hip/hip_runtime.h>

#define HIDDEN 128
#define NRAD 6
#define NEMB 95
#define PRS 132   // pps row stride (words)
#define WRS 132   // w3s row stride (shorts)
#define SCR 132   // per-wave scratch row stride (shorts)
#define NWAVES 12
#define NBLK 256

typedef short bf16x8 __attribute__((ext_vector_type(8)));
typedef float f32x4 __attribute__((ext_vector_type(4)));

__device__ __forceinline__ float fast_rcp(float x) { return __builtin_amdgcn_rcpf(x); }
__device__ __forceinline__ float swishf(float v) { return v * fast_rcp(1.0f + __expf(-v)); }
// float -> bf16 (round-to-nearest-even)
__device__ __forceinline__ short f2bf(float f) {
    union { float f; unsigned u; } c; c.f = f;
    unsigned r = (c.u + 0x7FFFu + ((c.u >> 16) & 1u)) >> 16;
    return (short)(unsigned short)r;
}
__device__ __forceinline__ float bf2f(unsigned short u) {
    union { unsigned u; float f; } c; c.u = ((unsigned)u) << 16; return c.f;
}
// pack two floats to packed-bf16 (truncated) in one v_perm_b32
__device__ __forceinline__ unsigned pk(float lo, float hi) {
    return __builtin_amdgcn_perm(__float_as_uint(hi), __float_as_uint(lo), 0x07060302u);
}
__device__ __forceinline__ float xlo(unsigned u) {
    union { unsigned u; float f; } c; c.u = u << 16; return c.f;
}
__device__ __forceinline__ float xhi(unsigned u) {
    union { unsigned u; float f; } c; c.u = u & 0xffff0000u; return c.f;
}
__device__ __forceinline__ void wait_lgkm() {
    asm volatile("s_waitcnt lgkmcnt(0)" ::: "memory");
}

// pPair[a][h] = (bf16(P2[a][h]) << 16) | bf16(P1[a][h])
__global__ void precompute_kernel(const float* __restrict__ emb,
                                  const float* __restrict__ w_lin,
                                  const float* __restrict__ b_lin,
                                  unsigned* __restrict__ pPair) {
    __shared__ __align__(16) float erow[HIDDEN];
    const int a = blockIdx.x;
    const int h = threadIdx.x;
    erow[h] = emb[a * HIDDEN + h];
    __syncthreads();
    float a1 = b_lin[h];
    float a2 = 0.f;
    const float* __restrict__ w1 = w_lin + h * 384;
    const float* __restrict__ w2 = w1 + HIDDEN;
#pragma unroll 8
    for (int k = 0; k < HIDDEN; ++k) {
        a1 += erow[k] * w1[k];
        a2 += erow[k] * w2[k];
    }
    const unsigned lo = (unsigned)(unsigned short)f2bf(a1);
    const unsigned hi = ((unsigned)(unsigned short)f2bf(a2)) << 16;
    pPair[a * HIDDEN + h] = hi | lo;
}

struct RawMD {
    float2 ra, rb, rc;   // rbf[e][0..5]
    int ii, jj;          // iv[e], jv[e]
};

__device__ __forceinline__ RawMD load_raw(int tile, int l15, int n_edges,
                                          const int* __restrict__ iv,
                                          const int* __restrict__ jv,
                                          const float* __restrict__ rbf) {
    int e = tile * 16 + l15;
    int ecl = (e < n_edges) ? e : (n_edges - 1);
    RawMD m;
    const float2* rp = reinterpret_cast<const float2*>(rbf + (size_t)ecl * NRAD);
    m.ra = rp[0];
    m.rb = rp[1];
    m.rc = rp[2];
    m.ii = iv[ecl];
    m.jj = jv[ecl];
    return m;
}

// Barrier-free wave-local kernel (r15 structure) with:
//  * 2-deep metadata pipeline: xv gathers for tile t+1 are issued BEFORE
//    tile t's stores, so the epilogue's wait on xi/xj never drains a recent
//    store burst (vmcnt retires in issue order).
//  * single-pass epilogue (r13 style): pps gathers issued once per tile;
//    stage e1 (16 edges) -> 8KB burst -> restage e2 -> 8KB burst.
// A-build via 8 MFMAs (aw0=[w0|b0] regs x rpad=[rbf|1]) + scratch bounce.
// W3/w1/pps in LDS.  NO s_barrier in the loop.  768-thread blocks, 12 waves.
__global__ __launch_bounds__(768)
void edge_mfma_kernel(const int* __restrict__ xv,
                      const float* __restrict__ rbf,
                      const int* __restrict__ iv,
                      const int* __restrict__ jv,
                      const float* __restrict__ w_rbf0,
                      const float* __restrict__ b_rbf0,
                      const float* __restrict__ w_rbf1,
                      const float* __restrict__ w_lin,
                      const unsigned* __restrict__ pPairG,
                      float* __restrict__ out_e1,
                      float* __restrict__ out_e2,
                      int n_edges, int nt16, int n_rows) {
    __shared__ unsigned pps[NEMB * PRS];                               // 50160 B
    __shared__ __align__(16) short w3s[HIDDEN * WRS];                  // 33792 B
    __shared__ __align__(16) short w1a[HIDDEN * 8];                    //  2048 B
    __shared__ __align__(16) unsigned short scratch[NWAVES][16 * SCR]; // 50688 B

    const int tid = threadIdx.x;

    // ---- stage packed P table (padded rows) ----
    {
        const int nr = (n_rows < NEMB ? n_rows : NEMB);
        for (int s = tid; s < nr * HIDDEN; s += 768) {
            pps[(s >> 7) * PRS + (s & 127)] = pPairG[s];
        }
    }
    // ---- stage W3 bf16 (row h, 16 octets of 8 k) ----
    for (int s = tid; s < HIDDEN * 16; s += 768) {
        const int h = s >> 4, oct = s & 15;
        const float4* s4 = reinterpret_cast<const float4*>(w_lin + h * 384 + 256 + oct * 8);
        const float4 va = s4[0];
        const float4 vb = s4[1];
        bf16x8 fr;
        fr[0] = f2bf(va.x); fr[1] = f2bf(va.y);
        fr[2] = f2bf(va.z); fr[3] = f2bf(va.w);
        fr[4] = f2bf(vb.x); fr[5] = f2bf(vb.y);
        fr[6] = f2bf(vb.z); fr[7] = f2bf(vb.w);
        *reinterpret_cast<bf16x8*>(&w3s[h * WRS + oct * 8]) = fr;
    }
    // ---- w1 rows bf16 (k-padded to 8) ----
    if (tid < HIDDEN) {
        bf16x8 f1;
#pragma unroll
        for (int r = 0; r < NRAD; ++r) f1[r] = f2bf(w_rbf1[tid * NRAD + r]);
        f1[6] = 0; f1[7] = 0;
        *reinterpret_cast<bf16x8*>(&w1a[tid * 8]) = f1;
    }

    const int wid = tid >> 6;
    const int lane = tid & 63;
    const int l15 = lane & 15;
    const int lg = lane >> 4;

    // ---- aw0 A-fragments: rows k=c*16+l15, cols [w0 r=0..5, b0, 0] ----
    bf16x8 aw0[8];
#pragma unroll
    for (int c = 0; c < 8; ++c) {
        bf16x8 fr = (bf16x8){0, 0, 0, 0, 0, 0, 0, 0};
        if (lg == 0) {
            const int k = c * 16 + l15;
#pragma unroll
            for (int r = 0; r < NRAD; ++r) fr[r] = f2bf(w_rbf0[k * NRAD + r]);
            fr[6] = f2bf(b_rbf0[k]);
            fr[7] = 0;
        }
        aw0[c] = fr;
    }
    __syncthreads();   // the ONLY block barrier

    unsigned short* const scr = &scratch[wid][0];
    const int gw = blockIdx.x * NWAVES + wid;
    const int NW = NBLK * NWAVES;
    const f32x4 zero4 = (f32x4){0.f, 0.f, 0.f, 0.f};

    int t = gw;
    if (t < nt16) {
        // ---- 2-deep prologue ----
        RawMD cur = load_raw(t, l15, n_edges, iv, jv, rbf);
        const int tn0 = (t + NW < nt16) ? t + NW : t;
        RawMD nxt = load_raw(tn0, l15, n_edges, iv, jv, rbf);
        int cxi = xv[cur.ii];
        int cxj = xv[cur.jj];

        for (; t < nt16; t += NW) {
            // issue t+2 raw MD and t+1 xv gathers NOW (before this tile's stores)
            const int t2 = (t + 2 * NW < nt16) ? t + 2 * NW : t;
            RawMD p2 = load_raw(t2, l15, n_edges, iv, jv, rbf);
            const int gxi = xv[nxt.ii];
            const int gxj = xv[nxt.jj];

            // ---- rpad B-operand [rbf, 1, 0] (nonzero only in lg==0) ----
            union { uint4 q; bf16x8 b; } rp;
            rp.q = (uint4){0u, 0u, 0u, 0u};
            if (lg == 0) {
                rp.q.x = pk(cur.ra.x, cur.ra.y);
                rp.q.y = pk(cur.rb.x, cur.rb.y);
                rp.q.z = pk(cur.rc.x, cur.rc.y);
                rp.q.w = pk(1.0f, 0.0f);
            }

            // ---- A-build via MFMA: C[k][e], lane -> k=c*16+lg*4+q, e=l15 ----
#pragma unroll
            for (int c = 0; c < 8; ++c) {
                const f32x4 cb = __builtin_amdgcn_mfma_f32_16x16x32_bf16(
                    aw0[c], rp.b, zero4, 0, 0, 0);
                const uint2 wv = make_uint2(pk(swishf(cb[0]), swishf(cb[1])),
                                            pk(swishf(cb[2]), swishf(cb[3])));
                *reinterpret_cast<uint2*>(&scr[l15 * SCR + c * 16 + lg * 4]) = wv;
            }

            // ---- qd = rbf @ w1^T via MFMA (w1 from LDS; fills bounce shadow) ----
            f32x4 acc2[8];
#pragma unroll
            for (int nt = 0; nt < 8; ++nt) {
                const bf16x8 aw = *reinterpret_cast<const bf16x8*>(
                    &w1a[(nt * 16 + l15) * 8]);
                acc2[nt] = __builtin_amdgcn_mfma_f32_16x16x32_bf16(aw, rp.b, zero4, 0, 0, 0);
            }

            wait_lgkm();   // in-wave: bounce writes visible

            bf16x8 bfrag[4];
#pragma unroll
            for (int ks = 0; ks < 4; ++ks)
                bfrag[ks] = *reinterpret_cast<const bf16x8*>(
                    &scr[l15 * SCR + ks * 32 + lg * 8]);

            // ---- main MFMA: C[ch][e], lane -> (e=l15, ch=nt*16+lg*4+q) ----
            f32x4 acc[8];
#pragma unroll
            for (int nt = 0; nt < 8; ++nt) acc[nt] = zero4;
#pragma unroll
            for (int ks = 0; ks < 4; ++ks)
#pragma unroll
                for (int nt = 0; nt < 8; ++nt) {
                    const bf16x8 wfr = *reinterpret_cast<const bf16x8*>(
                        &w3s[(nt * 16 + l15) * WRS + (ks * 4 + lg) * 8]);
                    acc[nt] = __builtin_amdgcn_mfma_f32_16x16x32_bf16(
                        wfr, bfrag[ks], acc[nt], 0, 0, 0);
                }

            wait_lgkm();   // in-wave WAR: bfrag reads done before scratch reuse

            // ---- single-pass epilogue: P adds + swish; stage e1 ----
#pragma unroll
            for (int nt = 0; nt < 8; ++nt) {
                const int ch0 = nt * 16 + lg * 4;
                const uint4 r1 = *reinterpret_cast<const uint4*>(&pps[cxi * PRS + ch0]);
                const uint4 r2 = *reinterpret_cast<const uint4*>(&pps[cxj * PRS + ch0]);
                const unsigned rr1[4] = {r1.x, r1.y, r1.z, r1.w};
                const unsigned rr2[4] = {r2.x, r2.y, r2.z, r2.w};
                float e1v[4];
#pragma unroll
                for (int q = 0; q < 4; ++q) {
                    const float pv = bf2f((unsigned short)(rr1[q] & 0xffff))
                                   + bf2f((unsigned short)(rr2[q] >> 16));
                    const float sm = acc[nt][q] + pv;
                    e1v[q] = swishf(sm);
                    acc2[nt][q] *= e1v[q];      // e2 kept in regs
                }
                *reinterpret_cast<uint2*>(&scr[l15 * SCR + ch0]) =
                    make_uint2(pk(e1v[0], e1v[1]), pk(e1v[2], e1v[3]));
            }
            wait_lgkm();   // e1 stage visible (in-wave)

            // ---- store e1: 8KB contiguous burst ----
            const size_t base = (size_t)t * 16 * HIDDEN;
#pragma unroll
            for (int s2 = 0; s2 < 8; ++s2) {
                const int idx = s2 * 256 + lane * 4;
                const int e_l = idx >> 7;
                const int ch = idx & 127;
                const uint2 uv = *reinterpret_cast<const uint2*>(&scr[e_l * SCR + ch]);
                if (t * 16 + e_l < n_edges) {
                    f32x4 v;
                    v[0] = xlo(uv.x); v[1] = xhi(uv.x);
                    v[2] = xlo(uv.y); v[3] = xhi(uv.y);
                    *reinterpret_cast<f32x4*>(out_e1 + base + idx) = v;
                }
            }
            wait_lgkm();   // e1 stage reads drained

            // ---- stage e2, store e2 ----
#pragma unroll
            for (int nt = 0; nt < 8; ++nt) {
                const int ch0 = nt * 16 + lg * 4;
                *reinterpret_cast<uint2*>(&scr[l15 * SCR + ch0]) =
                    make_uint2(pk(acc2[nt][0], acc2[nt][1]), pk(acc2[nt][2], acc2[nt][3]));
            }
            wait_lgkm();   // e2 stage visible
#pragma unroll
            for (int s2 = 0; s2 < 8; ++s2) {
                const int idx = s2 * 256 + lane * 4;
                const int e_l = idx >> 7;
                const int ch = idx & 127;
                const uint2 uv = *reinterpret_cast<const uint2*>(&scr[e_l * SCR + ch]);
                if (t * 16 + e_l < n_edges) {
                    f32x4 v;
                    v[0] = xlo(uv.x); v[1] = xhi(uv.x);
                    v[2] = xlo(uv.y); v[3] = xhi(uv.y);
                    *reinterpret_cast<f32x4*>(out_e2 + base + idx) = v;
                }
            }
            wait_lgkm();   // e2 stage reads drained before next tile's bounce

            cur = nxt; nxt = p2; cxi = gxi; cxj = gxj;
        }
    }
}

extern "C" void kernel_launch(void* const* d_in, const int* in_sizes, int n_in,
                              void* d_out, int out_size, void* d_ws, size_t ws_size,
                              hipStream_t stream) {
    const int*   xv     = (const int*)  d_in[0];
    const float* rbf    = (const float*)d_in[1];
    const int*   iv     = (const int*)  d_in[2];
    const int*   jv     = (const int*)  d_in[3];
    const float* emb    = (const float*)d_in[4];
    const float* w_rbf0 = (const float*)d_in[5];
    const float* b_rbf0 = (const float*)d_in[6];
    const float* w_lin  = (const float*)d_in[7];
    const float* b_lin  = (const float*)d_in[8];
    const float* w_rbf1 = (const float*)d_in[9];

    const int n_edges = in_sizes[2];
    const int n_emb_rows = in_sizes[4] / HIDDEN;   // 95

    unsigned* pPair = (unsigned*)d_ws;             // 95*128*4 = 48640 B

    float* out_e1 = (float*)d_out;
    float* out_e2 = out_e1 + (size_t)n_edges * HIDDEN;

    precompute_kernel<<<n_emb_rows, HIDDEN, 0, stream>>>(emb, w_lin, b_lin, pPair);

    const int nt16 = (n_edges + 15) / 16;
    edge_mfma_kernel<<<NBLK, 768, 0, stream>>>(xv, rbf, iv, jv,
                                               w_rbf0, b_rbf0, w_rbf1, w_lin,
                                               pPair, out_e1, out_e2,
                                               n_edges, nt16, n_emb_rows);
}

// Round 17
// 143.766 us; speedup vs baseline: 1.1033x; 1.1033x over previous
//
#include <hip/hip_runtime.h>

#define HIDDEN 128
#define NRAD 6
#define NEMB 95
#define PRS 132   // pps row stride (words)
#define WRS 132   // w3s row stride (shorts)
#define SCR 132   // per-wave scratch row stride (shorts)
#define NWAVES 12
#define NBLK 256

typedef short bf16x8 __attribute__((ext_vector_type(8)));
typedef float f32x4 __attribute__((ext_vector_type(4)));

__device__ __forceinline__ float fast_rcp(float x) { return __builtin_amdgcn_rcpf(x); }
__device__ __forceinline__ float swishf(float v) { return v * fast_rcp(1.0f + __expf(-v)); }
// float -> bf16 (round-to-nearest-even)
__device__ __forceinline__ short f2bf(float f) {
    union { float f; unsigned u; } c; c.f = f;
    unsigned r = (c.u + 0x7FFFu + ((c.u >> 16) & 1u)) >> 16;
    return (short)(unsigned short)r;
}
__device__ __forceinline__ float bf2f(unsigned short u) {
    union { unsigned u; float f; } c; c.u = ((unsigned)u) << 16; return c.f;
}
// pack two floats to packed-bf16 (truncated) in one v_perm_b32
__device__ __forceinline__ unsigned pk(float lo, float hi) {
    return __builtin_amdgcn_perm(__float_as_uint(hi), __float_as_uint(lo), 0x07060302u);
}
__device__ __forceinline__ float xlo(unsigned u) {
    union { unsigned u; float f; } c; c.u = u << 16; return c.f;
}
__device__ __forceinline__ float xhi(unsigned u) {
    union { unsigned u; float f; } c; c.u = u & 0xffff0000u; return c.f;
}
__device__ __forceinline__ void wait_lgkm() {
    asm volatile("s_waitcnt lgkmcnt(0)" ::: "memory");
}

// pPair[a][h] = (bf16(P2[a][h]) << 16) | bf16(P1[a][h])
__global__ void precompute_kernel(const float* __restrict__ emb,
                                  const float* __restrict__ w_lin,
                                  const float* __restrict__ b_lin,
                                  unsigned* __restrict__ pPair) {
    __shared__ __align__(16) float erow[HIDDEN];
    const int a = blockIdx.x;
    const int h = threadIdx.x;
    erow[h] = emb[a * HIDDEN + h];
    __syncthreads();
    float a1 = b_lin[h];
    float a2 = 0.f;
    const float* __restrict__ w1 = w_lin + h * 384;
    const float* __restrict__ w2 = w1 + HIDDEN;
#pragma unroll 8
    for (int k = 0; k < HIDDEN; ++k) {
        a1 += erow[k] * w1[k];
        a2 += erow[k] * w2[k];
    }
    const unsigned lo = (unsigned)(unsigned short)f2bf(a1);
    const unsigned hi = ((unsigned)(unsigned short)f2bf(a2)) << 16;
    pPair[a * HIDDEN + h] = hi | lo;
}

struct RawMD {
    float2 ra, rb, rc;   // rbf[e][0..5]
    int ii, jj;          // iv[e], jv[e]
};

__device__ __forceinline__ RawMD load_raw(int tile, int l15, int n_edges,
                                          const int* __restrict__ iv,
                                          const int* __restrict__ jv,
                                          const float* __restrict__ rbf) {
    int e = tile * 16 + l15;
    int ecl = (e < n_edges) ? e : (n_edges - 1);
    RawMD m;
    const float2* rp = reinterpret_cast<const float2*>(rbf + (size_t)ecl * NRAD);
    m.ra = rp[0];
    m.rb = rp[1];
    m.rc = rp[2];
    m.ii = iv[ecl];
    m.jj = jv[ecl];
    return m;
}

// Barrier-free wave-local kernel (proven 144.5 us structure, r15 re-submit).
// Per wave-tile (16 edges x 128 ch):
//   * rbf0 via 8 MFMAs (aw0=[w0|b0] regs x rpad=[rbf|1]) bounced through the
//     per-wave scratch (8 b64 writes + 4 b128 reads) to B-fragment layout.
//   * W3 (LDS), w1 (LDS), pps (LDS).  NO s_barrier in the loop.
//   * two-pass epilogue: each 8-edge half stages e1+e2 then burst-stores.
// 768-thread blocks (12 waves, 3/SIMD).
__global__ __launch_bounds__(768)
void edge_mfma_kernel(const int* __restrict__ xv,
                      const float* __restrict__ rbf,
                      const int* __restrict__ iv,
                      const int* __restrict__ jv,
                      const float* __restrict__ w_rbf0,
                      const float* __restrict__ b_rbf0,
                      const float* __restrict__ w_rbf1,
                      const float* __restrict__ w_lin,
                      const unsigned* __restrict__ pPairG,
                      float* __restrict__ out_e1,
                      float* __restrict__ out_e2,
                      int n_edges, int nt16, int n_rows) {
    __shared__ unsigned pps[NEMB * PRS];                               // 50160 B
    __shared__ __align__(16) short w3s[HIDDEN * WRS];                  // 33792 B
    __shared__ __align__(16) short w1a[HIDDEN * 8];                    //  2048 B
    __shared__ __align__(16) unsigned short scratch[NWAVES][16 * SCR]; // 50688 B

    const int tid = threadIdx.x;

    // ---- stage packed P table (padded rows) ----
    {
        const int nr = (n_rows < NEMB ? n_rows : NEMB);
        for (int s = tid; s < nr * HIDDEN; s += 768) {
            pps[(s >> 7) * PRS + (s & 127)] = pPairG[s];
        }
    }
    // ---- stage W3 bf16 (row h, 16 octets of 8 k) ----
    for (int s = tid; s < HIDDEN * 16; s += 768) {
        const int h = s >> 4, oct = s & 15;
        const float4* s4 = reinterpret_cast<const float4*>(w_lin + h * 384 + 256 + oct * 8);
        const float4 va = s4[0];
        const float4 vb = s4[1];
        bf16x8 fr;
        fr[0] = f2bf(va.x); fr[1] = f2bf(va.y);
        fr[2] = f2bf(va.z); fr[3] = f2bf(va.w);
        fr[4] = f2bf(vb.x); fr[5] = f2bf(vb.y);
        fr[6] = f2bf(vb.z); fr[7] = f2bf(vb.w);
        *reinterpret_cast<bf16x8*>(&w3s[h * WRS + oct * 8]) = fr;
    }
    // ---- w1 rows bf16 (k-padded to 8) ----
    if (tid < HIDDEN) {
        bf16x8 f1;
#pragma unroll
        for (int r = 0; r < NRAD; ++r) f1[r] = f2bf(w_rbf1[tid * NRAD + r]);
        f1[6] = 0; f1[7] = 0;
        *reinterpret_cast<bf16x8*>(&w1a[tid * 8]) = f1;
    }

    const int wid = tid >> 6;
    const int lane = tid & 63;
    const int l15 = lane & 15;
    const int lg = lane >> 4;

    // ---- aw0 A-fragments: rows k=c*16+l15, cols [w0 r=0..5, b0, 0] ----
    bf16x8 aw0[8];
#pragma unroll
    for (int c = 0; c < 8; ++c) {
        bf16x8 fr = (bf16x8){0, 0, 0, 0, 0, 0, 0, 0};
        if (lg == 0) {
            const int k = c * 16 + l15;
#pragma unroll
            for (int r = 0; r < NRAD; ++r) fr[r] = f2bf(w_rbf0[k * NRAD + r]);
            fr[6] = f2bf(b_rbf0[k]);
            fr[7] = 0;
        }
        aw0[c] = fr;
    }
    __syncthreads();   // the ONLY block barrier

    unsigned short* const scr = &scratch[wid][0];
    const int gw = blockIdx.x * NWAVES + wid;
    const int NW = NBLK * NWAVES;
    const f32x4 zero4 = (f32x4){0.f, 0.f, 0.f, 0.f};

    int t = gw;
    if (t < nt16) {
        RawMD cur = load_raw(t, l15, n_edges, iv, jv, rbf);
        for (; t < nt16; t += NW) {
            const int tn = (t + NW < nt16) ? t + NW : t;
            RawMD nxt = load_raw(tn, l15, n_edges, iv, jv, rbf);   // prefetch
            const int xi = xv[cur.ii];
            const int xj = xv[cur.jj];

            // ---- rpad B-operand [rbf, 1, 0] (nonzero only in lg==0) ----
            union { uint4 q; bf16x8 b; } rp;
            rp.q = (uint4){0u, 0u, 0u, 0u};
            if (lg == 0) {
                rp.q.x = pk(cur.ra.x, cur.ra.y);
                rp.q.y = pk(cur.rb.x, cur.rb.y);
                rp.q.z = pk(cur.rc.x, cur.rc.y);
                rp.q.w = pk(1.0f, 0.0f);
            }

            // ---- A-build via MFMA: C[k][e], lane -> k=c*16+lg*4+q, e=l15 ----
#pragma unroll
            for (int c = 0; c < 8; ++c) {
                const f32x4 cb = __builtin_amdgcn_mfma_f32_16x16x32_bf16(
                    aw0[c], rp.b, zero4, 0, 0, 0);
                const uint2 wv = make_uint2(pk(swishf(cb[0]), swishf(cb[1])),
                                            pk(swishf(cb[2]), swishf(cb[3])));
                *reinterpret_cast<uint2*>(&scr[l15 * SCR + c * 16 + lg * 4]) = wv;
            }

            // ---- qd = rbf @ w1^T via MFMA (w1 from LDS; fills bounce shadow) ----
            f32x4 acc2[8];
#pragma unroll
            for (int nt = 0; nt < 8; ++nt) {
                const bf16x8 aw = *reinterpret_cast<const bf16x8*>(
                    &w1a[(nt * 16 + l15) * 8]);
                acc2[nt] = __builtin_amdgcn_mfma_f32_16x16x32_bf16(aw, rp.b, zero4, 0, 0, 0);
            }

            wait_lgkm();   // in-wave: bounce writes visible

            bf16x8 bfrag[4];
#pragma unroll
            for (int ks = 0; ks < 4; ++ks)
                bfrag[ks] = *reinterpret_cast<const bf16x8*>(
                    &scr[l15 * SCR + ks * 32 + lg * 8]);

            // ---- main MFMA: C[ch][e], lane -> (e=l15, ch=nt*16+lg*4+q) ----
            f32x4 acc[8];
#pragma unroll
            for (int nt = 0; nt < 8; ++nt) acc[nt] = zero4;
#pragma unroll
            for (int ks = 0; ks < 4; ++ks)
#pragma unroll
                for (int nt = 0; nt < 8; ++nt) {
                    const bf16x8 wfr = *reinterpret_cast<const bf16x8*>(
                        &w3s[(nt * 16 + l15) * WRS + (ks * 4 + lg) * 8]);
                    acc[nt] = __builtin_amdgcn_mfma_f32_16x16x32_bf16(
                        wfr, bfrag[ks], acc[nt], 0, 0, 0);
                }

            // ---- epilogue + stores: two 8-edge passes through scratch ----
#pragma unroll
            for (int p = 0; p < 2; ++p) {
                if ((l15 >> 3) == p) {
                    const int so = (l15 & 7) * SCR;
#pragma unroll
                    for (int nt = 0; nt < 8; ++nt) {
                        const int ch0 = nt * 16 + lg * 4;
                        const uint4 r1 = *reinterpret_cast<const uint4*>(&pps[xi * PRS + ch0]);
                        const uint4 r2 = *reinterpret_cast<const uint4*>(&pps[xj * PRS + ch0]);
                        const unsigned rr1[4] = {r1.x, r1.y, r1.z, r1.w};
                        const unsigned rr2[4] = {r2.x, r2.y, r2.z, r2.w};
                        float e1v[4], e2v[4];
#pragma unroll
                        for (int q = 0; q < 4; ++q) {
                            const float pv = bf2f((unsigned short)(rr1[q] & 0xffff))
                                           + bf2f((unsigned short)(rr2[q] >> 16));
                            const float sm = acc[nt][q] + pv;
                            e1v[q] = swishf(sm);
                            e2v[q] = acc2[nt][q] * e1v[q];
                        }
                        *reinterpret_cast<uint2*>(&scr[so + ch0]) =
                            make_uint2(pk(e1v[0], e1v[1]), pk(e1v[2], e1v[3]));
                        *reinterpret_cast<uint2*>(&scr[(8 + (l15 & 7)) * SCR + ch0]) =
                            make_uint2(pk(e2v[0], e2v[1]), pk(e2v[2], e2v[3]));
                    }
                }
                wait_lgkm();   // in-wave: stage writes complete before reads

                const size_t base = ((size_t)t * 16 + p * 8) * HIDDEN;
#pragma unroll
                for (int arr = 0; arr < 2; ++arr) {
                    float* __restrict__ ob = arr ? out_e2 : out_e1;
#pragma unroll
                    for (int s2 = 0; s2 < 4; ++s2) {
                        const int idx = s2 * 256 + lane * 4;   // floats within 4KB
                        const int e_l = idx >> 7;
                        const int ch = idx & 127;
                        const uint2 uv = *reinterpret_cast<const uint2*>(
                            &scr[(arr * 8 + e_l) * SCR + ch]);
                        if (t * 16 + p * 8 + e_l < n_edges) {
                            f32x4 v;
                            v[0] = xlo(uv.x); v[1] = xhi(uv.x);
                            v[2] = xlo(uv.y); v[3] = xhi(uv.y);
                            *reinterpret_cast<f32x4*>(ob + base + idx) = v;
                        }
                    }
                }
                wait_lgkm();   // in-wave WAR: stage reads drained before next pass
            }
            cur = nxt;
        }
    }
}

extern "C" void kernel_launch(void* const* d_in, const int* in_sizes, int n_in,
                              void* d_out, int out_size, void* d_ws, size_t ws_size,
                              hipStream_t stream) {
    const int*   xv     = (const int*)  d_in[0];
    const float* rbf    = (const float*)d_in[1];
    const int*   iv     = (const int*)  d_in[2];
    const int*   jv     = (const int*)  d_in[3];
    const float* emb    = (const float*)d_in[4];
    const float* w_rbf0 = (const float*)d_in[5];
    const float* b_rbf0 = (const float*)d_in[6];
    const float* w_lin  = (const float*)d_in[7];
    const float* b_lin  = (const float*)d_in[8];
    const float* w_rbf1 = (const float*)d_in[9];

    const int n_edges = in_sizes[2];
    const int n_emb_rows = in_sizes[4] / HIDDEN;   // 95

    unsigned* pPair = (unsigned*)d_ws;             // 95*128*4 = 48640 B

    float* out_e1 = (float*)d_out;
    float* out_e2 = out_e1 + (size_t)n_edges * HIDDEN;

    precompute_kernel<<<n_emb_rows, HIDDEN, 0, stream>>>(emb, w_lin, b_lin, pPair);

    const int nt16 = (n_edges + 15) / 16;
    edge_mfma_kernel<<<NBLK, 768, 0, stream>>>(xv, rbf, iv, jv,
                                               w_rbf0, b_rbf0, w_rbf1, w_lin,
                                               pPair, out_e1, out_e2,
                                               n_edges, nt16, n_emb_rows);
}